// Round 1
// baseline (235.963 us; speedup 1.0000x reference)
//
#include <hip/hip_runtime.h>
#include <cstdint>

typedef short short8 __attribute__((ext_vector_type(8)));
typedef float floatx4 __attribute__((ext_vector_type(4)));

__device__ __forceinline__ unsigned short f2bf(float f) {
    unsigned int u = __builtin_bit_cast(unsigned int, f);
    u += 0x7FFFu + ((u >> 16) & 1u);
    return (unsigned short)(u >> 16);
}
__device__ __forceinline__ float bf2f(unsigned short h) {
    unsigned int u = ((unsigned int)h) << 16;
    return __builtin_bit_cast(float, u);
}

__device__ __forceinline__ void async_copy16(const void* g, void* lds) {
    __builtin_amdgcn_global_load_lds(
        (const __attribute__((address_space(1))) void*)g,
        (__attribute__((address_space(3))) void*)lds, 16, 0, 0);
}

// XOR swizzle (16-short granularity): slot koff = koff ^ (((row>>2)&3)<<4)
__device__ __forceinline__ int swz(int row, int koff) {
    return koff ^ (((row >> 2) & 3) << 4);
}

// ---------------------------------------------------------------------------
// m97-style bf16 MFMA GEMM (used for proj + final). C[m,n] = sum_k A[m,k]*B[n,k]
// AFP32: A fp32, staged via registers. EPI: 1 = bf16 +bias[n];
// 2 = fp32 gamma*(v+bias[n])+resid.
// ---------------------------------------------------------------------------
template<bool AFP32, int EPI>
__global__ __launch_bounds__(256) void mfma_gemm(
    const void* __restrict__ Avoid, const unsigned short* __restrict__ B,
    void* __restrict__ Cout, const float* __restrict__ bias,
    const float* __restrict__ gamma, const float* __restrict__ resid,
    int lda, int ldb, int ldc, int K)
{
    __shared__ unsigned short As[4096];   // [128][32] bf16
    __shared__ unsigned short Bs[4096];   // [128][32] bf16

    const int tid = threadIdx.x;
    const int wv = tid >> 6, ln = tid & 63;
    const int r16 = ln & 15, q8 = ln >> 4;
    const int wm = (wv >> 1) * 64, wn = (wv & 1) * 64;
    const int m0 = blockIdx.y * 128, n0 = blockIdx.x * 128;

    floatx4 acc[4][4] = {};

    for (int k0 = 0; k0 < K; k0 += 32) {
        if (AFP32) {
            const float* Af = (const float*)Avoid;
            #pragma unroll
            for (int p = 0; p < 4; ++p) {
                int u = p * 256 + tid;
                int row = u >> 3, c4 = u & 7;
                float4 v = *(const float4*)(Af + (size_t)(m0 + row) * lda + k0 + c4 * 4);
                ushort4 h;
                h.x = f2bf(v.x); h.y = f2bf(v.y); h.z = f2bf(v.z); h.w = f2bf(v.w);
                *(ushort4*)&As[row * 32 + c4 * 4] = h;
            }
            #pragma unroll
            for (int q = 0; q < 2; ++q) {
                int chunk = wv * 2 + q;
                int e = (chunk << 9) + ln * 8;
                int row = e >> 5, col = e & 31;
                async_copy16(B + (size_t)(n0 + row) * ldb + (k0 + col), &Bs[chunk << 9]);
            }
        } else {
            const unsigned short* Ag = (const unsigned short*)Avoid;
            #pragma unroll
            for (int q = 0; q < 2; ++q) {
                int chunk = wv * 2 + q;
                int e = (chunk << 9) + ln * 8;
                int row = e >> 5, col = e & 31;
                async_copy16(Ag + (size_t)(m0 + row) * lda + (k0 + col), &As[chunk << 9]);
                async_copy16(B + (size_t)(n0 + row) * ldb + (k0 + col), &Bs[chunk << 9]);
            }
        }
        __syncthreads();

        short8 af[4], bff[4];
        #pragma unroll
        for (int i = 0; i < 4; ++i) {
            af[i]  = *(const short8*)&As[(wm + i * 16 + r16) * 32 + q8 * 8];
            bff[i] = *(const short8*)&Bs[(wn + i * 16 + r16) * 32 + q8 * 8];
        }
        #pragma unroll
        for (int mi = 0; mi < 4; ++mi)
            #pragma unroll
            for (int ni = 0; ni < 4; ++ni)
                acc[mi][ni] = __builtin_amdgcn_mfma_f32_16x16x32_bf16(
                    af[mi], bff[ni], acc[mi][ni], 0, 0, 0);
        __syncthreads();
    }

    if (EPI == 2) {
        float* C = (float*)Cout;
        const float gm = gamma[0];
        #pragma unroll
        for (int ni = 0; ni < 4; ++ni) {
            const int n = n0 + wn + ni * 16 + r16;
            const float bs = bias[n];
            #pragma unroll
            for (int mi = 0; mi < 4; ++mi)
                #pragma unroll
                for (int r = 0; r < 4; ++r) {
                    int m = m0 + wm + mi * 16 + q8 * 4 + r;
                    C[(size_t)m * ldc + n] = gm * (acc[mi][ni][r] + bs) + resid[(size_t)m * ldc + n];
                }
        }
    } else {
        unsigned short* C = (unsigned short*)Cout;
        #pragma unroll
        for (int ni = 0; ni < 4; ++ni) {
            const int n = n0 + wn + ni * 16 + r16;
            const float bs = bias[n];
            #pragma unroll
            for (int mi = 0; mi < 4; ++mi)
                #pragma unroll
                for (int r = 0; r < 4; ++r) {
                    int m = m0 + wm + mi * 16 + q8 * 4 + r;
                    C[(size_t)m * ldc + n] = f2bf(acc[mi][ni][r] + bs);
                }
        }
    }
}

// ---------------------------------------------------------------------------
// Phase 1: l[b][i] = sum_j exp(theta[b,j].phi[b,i] - 20)
// Grid (4 j-splits, 16 i-tiles of 64, 8 b) = 512 blocks.
// ---------------------------------------------------------------------------
__global__ __launch_bounds__(256) void phase1_l_kernel(
    const unsigned short* __restrict__ tpgF,   // [32768][384], theta cols 0..63
    const unsigned short* __restrict__ phiP,   // [8][1024][64]
    float* __restrict__ lbuf)                  // [8][1024] (pre-zeroed)
{
    __shared__ unsigned short th_s[8192];   // [128][64]
    __shared__ unsigned short ph_s[4096];   // [64][64]
    const int tid = threadIdx.x, wv = tid >> 6, ln = tid & 63;
    const int r16 = ln & 15, q8 = ln >> 4, lsub = ln >> 3, l8 = ln & 7;
    const int jsp = blockIdx.x, i0 = blockIdx.y * 64, b = blockIdx.z;

    #pragma unroll
    for (int q = 0; q < 2; ++q) {
        int chunk = wv * 2 + q, row = chunk * 8 + lsub;
        int so = swz(row, l8 * 8);
        async_copy16(phiP + (size_t)(b * 1024 + i0 + row) * 64 + so, &ph_s[chunk * 512]);
    }

    float colsum[4] = {0.f, 0.f, 0.f, 0.f};
    for (int jc = 0; jc < 8; ++jc) {
        const int j0 = jsp * 1024 + jc * 128;
        __syncthreads();
        #pragma unroll
        for (int q = 0; q < 4; ++q) {
            int chunk = wv * 4 + q, row = chunk * 8 + lsub;
            int so = swz(row, l8 * 8);
            async_copy16(tpgF + (size_t)(b * 4096 + j0 + row) * 384 + so, &th_s[chunk * 512]);
        }
        __syncthreads();

        floatx4 sacc[2][4] = {};
        #pragma unroll
        for (int ks = 0; ks < 2; ++ks) {
            short8 af[2], bf[4];
            #pragma unroll
            for (int mi = 0; mi < 2; ++mi)
                af[mi] = *(const short8*)&th_s[(wv * 32 + mi * 16 + r16) * 64 + swz(r16, ks * 32 + q8 * 8)];
            #pragma unroll
            for (int ni = 0; ni < 4; ++ni)
                bf[ni] = *(const short8*)&ph_s[(ni * 16 + r16) * 64 + swz(r16, ks * 32 + q8 * 8)];
            #pragma unroll
            for (int mi = 0; mi < 2; ++mi)
                #pragma unroll
                for (int ni = 0; ni < 4; ++ni)
                    sacc[mi][ni] = __builtin_amdgcn_mfma_f32_16x16x32_bf16(
                        af[mi], bf[ni], sacc[mi][ni], 0, 0, 0);
        }
        #pragma unroll
        for (int mi = 0; mi < 2; ++mi)
            #pragma unroll
            for (int ni = 0; ni < 4; ++ni)
                #pragma unroll
                for (int r = 0; r < 4; ++r)
                    colsum[ni] += __expf(sacc[mi][ni][r] - 20.f);
    }
    #pragma unroll
    for (int ni = 0; ni < 4; ++ni) {
        float s = colsum[ni];
        s += __shfl_xor(s, 16);
        s += __shfl_xor(s, 32);
        if (q8 == 0) atomicAdd(&lbuf[b * 1024 + i0 + ni * 16 + r16], s);
    }
}

// ---------------------------------------------------------------------------
// Fused attention phase 2: o[b,j,c] = sum_i exp(theta[j].phi[i]-20) * g'[c,i]
// (g' pre-scaled by 1/l). j-tile 64, c full 256, i chunks of 64. Grid (64, 8).
// ---------------------------------------------------------------------------
__global__ __launch_bounds__(256) void attn_fused_kernel(
    const unsigned short* __restrict__ tpgF,  // [32768][384], theta cols 0..63
    const unsigned short* __restrict__ phiP,  // [8][1024][64]
    const unsigned short* __restrict__ gPT,   // [8][256][1024], pre-scaled 1/l
    unsigned short* __restrict__ o_)          // [8][4096][256]
{
    __shared__ unsigned short th_es[4096];    // theta [64][64], then es (aliased)
    __shared__ unsigned short ph_s[4096];     // phi chunk [64][64]
    __shared__ unsigned short gs[16384];      // g chunk [256][64]

    const int tid = threadIdx.x, wv = tid >> 6, ln = tid & 63;
    const int r16 = ln & 15, q8 = ln >> 4, lsub = ln >> 3, l8 = ln & 7;
    const int j0 = blockIdx.x * 64, b = blockIdx.y;

    // stage theta tile [64][64] (swizzled), hoist to registers
    #pragma unroll
    for (int q = 0; q < 2; ++q) {
        int chunk = wv * 2 + q, row = chunk * 8 + lsub;
        int so = swz(row, l8 * 8);
        async_copy16(tpgF + (size_t)(b * 4096 + j0 + row) * 384 + so, &th_es[chunk * 512]);
    }
    __syncthreads();
    short8 thf[4][2];
    #pragma unroll
    for (int mi = 0; mi < 4; ++mi)
        #pragma unroll
        for (int ks = 0; ks < 2; ++ks)
            thf[mi][ks] = *(const short8*)&th_es[(mi * 16 + r16) * 64 + swz(r16, ks * 32 + q8 * 8)];

    floatx4 acc[4][4] = {};

    for (int i0 = 0; i0 < 1024; i0 += 64) {
        __syncthreads();   // prev o-MFMA done (and th reg-loads on first iter)
        #pragma unroll
        for (int q = 0; q < 2; ++q) {
            int chunk = wv * 2 + q, row = chunk * 8 + lsub;
            int so = swz(row, l8 * 8);
            async_copy16(phiP + (size_t)(b * 1024 + i0 + row) * 64 + so, &ph_s[chunk * 512]);
        }
        #pragma unroll
        for (int q = 0; q < 8; ++q) {
            int chunk = wv * 8 + q, c = chunk * 8 + lsub;
            int so = swz(c, l8 * 8);
            async_copy16(gPT + ((size_t)(b * 256 + c)) * 1024 + i0 + so, &gs[chunk * 512]);
        }
        __syncthreads();   // staging landed

        // s = theta . phi^T for i-cols [wv*16, wv*16+16)
        floatx4 sacc[4] = {};
        #pragma unroll
        for (int ks = 0; ks < 2; ++ks) {
            short8 pf = *(const short8*)&ph_s[(wv * 16 + r16) * 64 + swz(r16, ks * 32 + q8 * 8)];
            #pragma unroll
            for (int mi = 0; mi < 4; ++mi)
                sacc[mi] = __builtin_amdgcn_mfma_f32_16x16x32_bf16(
                    thf[mi][ks], pf, sacc[mi], 0, 0, 0);
        }
        // es[j][i] = exp(s - 20), swizzled store (conflict-free)
        #pragma unroll
        for (int mi = 0; mi < 4; ++mi)
            #pragma unroll
            for (int r = 0; r < 4; ++r) {
                int j = mi * 16 + q8 * 4 + r;           // (j>>2)&3 == q8
                th_es[j * 64 + (((wv ^ q8) << 4) | r16)] = f2bf(__expf(sacc[mi][r] - 20.f));
            }
        __syncthreads();   // es ready

        // o += es . gs^T  (c-cols wv*64..wv*64+64)
        #pragma unroll
        for (int ks = 0; ks < 2; ++ks) {
            short8 ef[4], gf[4];
            #pragma unroll
            for (int mi = 0; mi < 4; ++mi)
                ef[mi] = *(const short8*)&th_es[(mi * 16 + r16) * 64 + swz(r16, ks * 32 + q8 * 8)];
            #pragma unroll
            for (int ni = 0; ni < 4; ++ni)
                gf[ni] = *(const short8*)&gs[(wv * 64 + ni * 16 + r16) * 64 + swz(r16, ks * 32 + q8 * 8)];
            #pragma unroll
            for (int mi = 0; mi < 4; ++mi)
                #pragma unroll
                for (int ni = 0; ni < 4; ++ni)
                    acc[mi][ni] = __builtin_amdgcn_mfma_f32_16x16x32_bf16(
                        ef[mi], gf[ni], acc[mi][ni], 0, 0, 0);
        }
    }

    #pragma unroll
    for (int mi = 0; mi < 4; ++mi)
        #pragma unroll
        for (int ni = 0; ni < 4; ++ni)
            #pragma unroll
            for (int r = 0; r < 4; ++r) {
                int j = j0 + mi * 16 + q8 * 4 + r;
                int c = wv * 64 + ni * 16 + r16;
                o_[((size_t)b * 4096 + j) * 256 + c] = f2bf(acc[mi][ni][r]);
            }
}

// ---------------------------------------------------------------------------
// prep: weight transpose+cast [384][512] (theta|phi|g), o3wT [512][256],
// fused bias [384], zero lbuf.
// ---------------------------------------------------------------------------
__global__ __launch_bounds__(256) void prep_w_kernel(
    const float* __restrict__ theta_w, const float* __restrict__ phi_w,
    const float* __restrict__ g_w, const float* __restrict__ o3_w,
    const float* __restrict__ theta_b, const float* __restrict__ phi_b,
    const float* __restrict__ g_b,
    unsigned short* __restrict__ tpgwT, unsigned short* __restrict__ o3wT,
    float* __restrict__ biasTPG, float* __restrict__ lbuf)
{
    int t = blockIdx.x * 256 + threadIdx.x;
    if (t < 196608) {                      // tpgwT [384][512]
        int n = t >> 9, k = t & 511;
        float v = (n < 64) ? theta_w[k * 64 + n]
                : (n < 128) ? phi_w[k * 64 + (n - 64)]
                : g_w[k * 256 + (n - 128)];
        tpgwT[t] = f2bf(v);
    } else if (t < 327680) {               // o3wT [512][256]
        int e = t - 196608; int n = e >> 8, k = e & 255;
        o3wT[e] = f2bf(o3_w[k * 512 + n]);
    } else if (t < 328064) {               // biasTPG [384]
        int j = t - 327680;
        biasTPG[j] = (j < 64) ? theta_b[j] : (j < 128) ? phi_b[j - 64] : g_b[j - 128];
    } else if (t < 336256) {
        lbuf[t - 328064] = 0.f;
    }
}

// phi maxpool: tpgF cols [64,128) -> phiP [8][1024][64] bf16
__global__ __launch_bounds__(256) void maxpool_phi_kernel(
    const unsigned short* __restrict__ tpgF, unsigned short* __restrict__ phiP)
{
    int t = blockIdx.x * 256 + threadIdx.x;   // 524288
    int f = t & 63, i = (t >> 6) & 1023, b = t >> 16;
    int ph = i >> 5, pw = i & 31;
    size_t base = ((size_t)(b * 64 + 2 * ph) * 64 + 2 * pw) * 384 + 64 + f;
    float v0 = bf2f(tpgF[base]),         v1 = bf2f(tpgF[base + 384]);
    float v2 = bf2f(tpgF[base + 24576]), v3 = bf2f(tpgF[base + 24576 + 384]);
    phiP[t] = f2bf(fmaxf(fmaxf(v0, v1), fmaxf(v2, v3)));
}

// g maxpool + transpose + 1/l scale: tpgF cols [128,384) -> gPT [8][256][1024]
__global__ __launch_bounds__(256) void maxpoolT_g_kernel(
    const unsigned short* __restrict__ tpgF, const float* __restrict__ lbuf,
    unsigned short* __restrict__ gPT)
{
    __shared__ unsigned short tile[16][256];
    __shared__ float rls[16];
    int b = blockIdx.y, i0 = blockIdx.x * 16, c = threadIdx.x;
    if (c < 16) rls[c] = 1.0f / lbuf[b * 1024 + i0 + c];
    __syncthreads();
    #pragma unroll
    for (int il = 0; il < 16; ++il) {
        int i = i0 + il, ph = i >> 5, pw = i & 31;
        size_t base = ((size_t)(b * 64 + 2 * ph) * 64 + 2 * pw) * 384 + 128 + c;
        float v0 = bf2f(tpgF[base]),         v1 = bf2f(tpgF[base + 384]);
        float v2 = bf2f(tpgF[base + 24576]), v3 = bf2f(tpgF[base + 24576 + 384]);
        tile[il][c] = f2bf(fmaxf(fmaxf(v0, v1), fmaxf(v2, v3)) * rls[il]);
    }
    __syncthreads();
    unsigned short* dst = gPT + ((size_t)(b * 256 + c) * 1024 + i0);
    short8 v0, v1;
    #pragma unroll
    for (int il = 0; il < 8; ++il) { v0[il] = (short)tile[il][c]; v1[il] = (short)tile[il + 8][c]; }
    *(short8*)dst = v0;
    *(short8*)(dst + 8) = v1;
}

// ---------------------------------------------------------------------------
extern "C" void kernel_launch(void* const* d_in, const int* in_sizes, int n_in,
                              void* d_out, int out_size, void* d_ws, size_t ws_size,
                              hipStream_t stream)
{
    const float* x       = (const float*)d_in[0];
    const float* theta_w = (const float*)d_in[1];
    const float* theta_b = (const float*)d_in[2];
    const float* phi_w   = (const float*)d_in[3];
    const float* phi_b   = (const float*)d_in[4];
    const float* g_w     = (const float*)d_in[5];
    const float* g_b     = (const float*)d_in[6];
    const float* o3_w    = (const float*)d_in[7];
    const float* o3_b    = (const float*)d_in[8];
    const float* gamma   = (const float*)d_in[9];

    char* ws = (char*)d_ws;
    unsigned short* tpgwT  = (unsigned short*)(ws);             // 384x512 bf16
    unsigned short* o3wT   = (unsigned short*)(ws + 393216);    // 512x256
    float* biasTPG         = (float*)(ws + 655360);             // 384
    float* lbuf            = (float*)(ws + 656896);             // 8192
    unsigned short* tpgF   = (unsigned short*)(ws + (1u << 20));            // 24 MiB
    unsigned short* phiP   = (unsigned short*)(ws + (1u << 20) + 25165824); // 1 MiB
    unsigned short* gPT    = (unsigned short*)(ws + (1u << 20) + 26214400); // 4 MiB
    unsigned short* o_     = (unsigned short*)(ws + (1u << 20) + 30408704); // 16 MiB

    // 1. weight prep + lbuf zero
    prep_w_kernel<<<1314, 256, 0, stream>>>(theta_w, phi_w, g_w, o3_w,
                                            theta_b, phi_b, g_b,
                                            tpgwT, o3wT, biasTPG, lbuf);
    // 2. fused projections: tpgF = x . tpgwT^T + bias  [32768][384]
    mfma_gemm<true, 1><<<dim3(3, 256), 256, 0, stream>>>(
        x, tpgwT, tpgF, biasTPG, nullptr, nullptr, 512, 512, 384, 512);
    // 3. phi pool
    maxpool_phi_kernel<<<2048, 256, 0, stream>>>(tpgF, phiP);
    // 4. phase 1: l[b][i] = sum_j exp(theta[j].phi[i] - 20)
    phase1_l_kernel<<<dim3(4, 16, 8), 256, 0, stream>>>(tpgF, phiP, lbuf);
    // 5. g pool + transpose + 1/l scale
    maxpoolT_g_kernel<<<dim3(64, 8), 256, 0, stream>>>(tpgF, lbuf, gPT);
    // 6. phase 2: fused e-recompute + o = e . g'   [8][4096][256]
    attn_fused_kernel<<<dim3(64, 8), 256, 0, stream>>>(tpgF, phiP, gPT, o_);
    // 7. out = gamma*(o . o3wT^T + o3_b) + x   [32768][512] fp32
    mfma_gemm<false, 2><<<dim3(4, 256), 256, 0, stream>>>(
        o_, o3wT, d_out, o3_b, gamma, x, 256, 256, 512, 256);
}

// Round 2
// 233.098 us; speedup vs baseline: 1.0123x; 1.0123x over previous
//
#include <hip/hip_runtime.h>
#include <cstdint>

typedef short short8 __attribute__((ext_vector_type(8)));
typedef float floatx4 __attribute__((ext_vector_type(4)));

__device__ __forceinline__ unsigned short f2bf(float f) {
    unsigned int u = __builtin_bit_cast(unsigned int, f);
    u += 0x7FFFu + ((u >> 16) & 1u);
    return (unsigned short)(u >> 16);
}
__device__ __forceinline__ float bf2f(unsigned short h) {
    unsigned int u = ((unsigned int)h) << 16;
    return __builtin_bit_cast(float, u);
}

__device__ __forceinline__ void async_copy16(const void* g, void* lds) {
    __builtin_amdgcn_global_load_lds(
        (const __attribute__((address_space(1))) void*)g,
        (__attribute__((address_space(3))) void*)lds, 16, 0, 0);
}

// XOR swizzle (16-short granularity): slot koff = koff ^ (((row>>2)&3)<<4)
__device__ __forceinline__ int swz(int row, int koff) {
    return koff ^ (((row >> 2) & 3) << 4);
}

// ---------------------------------------------------------------------------
// m97-style bf16 MFMA GEMM (used for proj + final). C[m,n] = sum_k A[m,k]*B[n,k]
// AFP32: A fp32, staged via registers. EPI: 1 = bf16 +bias[n];
// 2 = fp32 gamma*(v+bias[n])+resid.
// ---------------------------------------------------------------------------
template<bool AFP32, int EPI>
__global__ __launch_bounds__(256) void mfma_gemm(
    const void* __restrict__ Avoid, const unsigned short* __restrict__ B,
    void* __restrict__ Cout, const float* __restrict__ bias,
    const float* __restrict__ gamma, const float* __restrict__ resid,
    int lda, int ldb, int ldc, int K)
{
    __shared__ unsigned short As[4096];   // [128][32] bf16
    __shared__ unsigned short Bs[4096];   // [128][32] bf16

    const int tid = threadIdx.x;
    const int wv = tid >> 6, ln = tid & 63;
    const int r16 = ln & 15, q8 = ln >> 4;
    const int wm = (wv >> 1) * 64, wn = (wv & 1) * 64;
    const int m0 = blockIdx.y * 128, n0 = blockIdx.x * 128;

    floatx4 acc[4][4] = {};

    for (int k0 = 0; k0 < K; k0 += 32) {
        if (AFP32) {
            const float* Af = (const float*)Avoid;
            #pragma unroll
            for (int p = 0; p < 4; ++p) {
                int u = p * 256 + tid;
                int row = u >> 3, c4 = u & 7;
                float4 v = *(const float4*)(Af + (size_t)(m0 + row) * lda + k0 + c4 * 4);
                ushort4 h;
                h.x = f2bf(v.x); h.y = f2bf(v.y); h.z = f2bf(v.z); h.w = f2bf(v.w);
                *(ushort4*)&As[row * 32 + c4 * 4] = h;
            }
            #pragma unroll
            for (int q = 0; q < 2; ++q) {
                int chunk = wv * 2 + q;
                int e = (chunk << 9) + ln * 8;
                int row = e >> 5, col = e & 31;
                async_copy16(B + (size_t)(n0 + row) * ldb + (k0 + col), &Bs[chunk << 9]);
            }
        } else {
            const unsigned short* Ag = (const unsigned short*)Avoid;
            #pragma unroll
            for (int q = 0; q < 2; ++q) {
                int chunk = wv * 2 + q;
                int e = (chunk << 9) + ln * 8;
                int row = e >> 5, col = e & 31;
                async_copy16(Ag + (size_t)(m0 + row) * lda + (k0 + col), &As[chunk << 9]);
                async_copy16(B + (size_t)(n0 + row) * ldb + (k0 + col), &Bs[chunk << 9]);
            }
        }
        __syncthreads();

        short8 af[4], bff[4];
        #pragma unroll
        for (int i = 0; i < 4; ++i) {
            af[i]  = *(const short8*)&As[(wm + i * 16 + r16) * 32 + q8 * 8];
            bff[i] = *(const short8*)&Bs[(wn + i * 16 + r16) * 32 + q8 * 8];
        }
        #pragma unroll
        for (int mi = 0; mi < 4; ++mi)
            #pragma unroll
            for (int ni = 0; ni < 4; ++ni)
                acc[mi][ni] = __builtin_amdgcn_mfma_f32_16x16x32_bf16(
                    af[mi], bff[ni], acc[mi][ni], 0, 0, 0);
        __syncthreads();
    }

    if (EPI == 2) {
        float* C = (float*)Cout;
        const float gm = gamma[0];
        #pragma unroll
        for (int ni = 0; ni < 4; ++ni) {
            const int n = n0 + wn + ni * 16 + r16;
            const float bs = bias[n];
            #pragma unroll
            for (int mi = 0; mi < 4; ++mi)
                #pragma unroll
                for (int r = 0; r < 4; ++r) {
                    int m = m0 + wm + mi * 16 + q8 * 4 + r;
                    C[(size_t)m * ldc + n] = gm * (acc[mi][ni][r] + bs) + resid[(size_t)m * ldc + n];
                }
        }
    } else {
        unsigned short* C = (unsigned short*)Cout;
        #pragma unroll
        for (int ni = 0; ni < 4; ++ni) {
            const int n = n0 + wn + ni * 16 + r16;
            const float bs = bias[n];
            #pragma unroll
            for (int mi = 0; mi < 4; ++mi)
                #pragma unroll
                for (int r = 0; r < 4; ++r) {
                    int m = m0 + wm + mi * 16 + q8 * 4 + r;
                    C[(size_t)m * ldc + n] = f2bf(acc[mi][ni][r] + bs);
                }
        }
    }
}

// ---------------------------------------------------------------------------
// Phase 1: l[b][i] = sum_j exp(theta[b,j].phi[b,i] - 20)
// Grid (4 j-splits, 16 i-tiles of 64, 8 b) = 512 blocks.
// ---------------------------------------------------------------------------
__global__ __launch_bounds__(256) void phase1_l_kernel(
    const unsigned short* __restrict__ tpgF,   // [32768][384], theta cols 0..63
    const unsigned short* __restrict__ phiP,   // [8][1024][64]
    float* __restrict__ lbuf)                  // [8][1024] (pre-zeroed)
{
    __shared__ unsigned short th_s[8192];   // [128][64]
    __shared__ unsigned short ph_s[4096];   // [64][64]
    const int tid = threadIdx.x, wv = tid >> 6, ln = tid & 63;
    const int r16 = ln & 15, q8 = ln >> 4, lsub = ln >> 3, l8 = ln & 7;
    const int jsp = blockIdx.x, i0 = blockIdx.y * 64, b = blockIdx.z;

    #pragma unroll
    for (int q = 0; q < 2; ++q) {
        int chunk = wv * 2 + q, row = chunk * 8 + lsub;
        int so = swz(row, l8 * 8);
        async_copy16(phiP + (size_t)(b * 1024 + i0 + row) * 64 + so, &ph_s[chunk * 512]);
    }

    float colsum[4] = {0.f, 0.f, 0.f, 0.f};
    for (int jc = 0; jc < 8; ++jc) {
        const int j0 = jsp * 1024 + jc * 128;
        __syncthreads();
        #pragma unroll
        for (int q = 0; q < 4; ++q) {
            int chunk = wv * 4 + q, row = chunk * 8 + lsub;
            int so = swz(row, l8 * 8);
            async_copy16(tpgF + (size_t)(b * 4096 + j0 + row) * 384 + so, &th_s[chunk * 512]);
        }
        __syncthreads();

        floatx4 sacc[2][4] = {};
        #pragma unroll
        for (int ks = 0; ks < 2; ++ks) {
            short8 af[2], bf[4];
            #pragma unroll
            for (int mi = 0; mi < 2; ++mi)
                af[mi] = *(const short8*)&th_s[(wv * 32 + mi * 16 + r16) * 64 + swz(r16, ks * 32 + q8 * 8)];
            #pragma unroll
            for (int ni = 0; ni < 4; ++ni)
                bf[ni] = *(const short8*)&ph_s[(ni * 16 + r16) * 64 + swz(r16, ks * 32 + q8 * 8)];
            #pragma unroll
            for (int mi = 0; mi < 2; ++mi)
                #pragma unroll
                for (int ni = 0; ni < 4; ++ni)
                    sacc[mi][ni] = __builtin_amdgcn_mfma_f32_16x16x32_bf16(
                        af[mi], bf[ni], sacc[mi][ni], 0, 0, 0);
        }
        #pragma unroll
        for (int mi = 0; mi < 2; ++mi)
            #pragma unroll
            for (int ni = 0; ni < 4; ++ni)
                #pragma unroll
                for (int r = 0; r < 4; ++r)
                    colsum[ni] += __expf(sacc[mi][ni][r] - 20.f);
    }
    #pragma unroll
    for (int ni = 0; ni < 4; ++ni) {
        float s = colsum[ni];
        s += __shfl_xor(s, 16);
        s += __shfl_xor(s, 32);
        if (q8 == 0) atomicAdd(&lbuf[b * 1024 + i0 + ni * 16 + r16], s);
    }
}

// ---------------------------------------------------------------------------
// Fused attention phase 2: o[b,j,c] = sum_i exp(theta[j].phi[i]-20) * g'[c,i]
// (g' pre-scaled by 1/l). j-tile 128, 8 waves (512 thr), i chunks of 64,
// double-buffered ph/gs staging with counted vmcnt (T3/T4 2-phase pipeline).
// Grid (32, 8) = 256 blocks, 96 KiB LDS, 1 block/CU.
// ---------------------------------------------------------------------------
__global__ __launch_bounds__(512) void attn_fused_kernel(
    const unsigned short* __restrict__ tpgF,  // [32768][384], theta cols 0..63
    const unsigned short* __restrict__ phiP,  // [8][1024][64]
    const unsigned short* __restrict__ gPT,   // [8][256][1024], pre-scaled 1/l
    unsigned short* __restrict__ o_)          // [8][4096][256]
{
    __shared__ unsigned short th_es[8192];     // theta [128][64], then es (aliased)
    __shared__ unsigned short ph_s[2][4096];   // phi chunk [64][64] x2
    __shared__ unsigned short gs[2][16384];    // g chunk [256][64] x2

    const int tid = threadIdx.x, wv = tid >> 6, ln = tid & 63;
    const int r16 = ln & 15, q8 = ln >> 4, lsub = ln >> 3, l8 = ln & 7;
    const int j0 = blockIdx.x * 128, b = blockIdx.y;
    const int jh = wv >> 2, it = wv & 3;  // j-half (QK/PV rows), i-tile / c-quarter

    // prologue: stage theta [128][64] (2/wave) + chunk0 ph+gs (5/wave)
    #pragma unroll
    for (int q = 0; q < 2; ++q) {
        int chunk = wv * 2 + q, row = chunk * 8 + lsub;
        async_copy16(tpgF + (size_t)(b * 4096 + j0 + row) * 384 + swz(row, l8 * 8),
                     &th_es[chunk * 512]);
    }
    {
        int row = wv * 8 + lsub;
        async_copy16(phiP + (size_t)(b * 1024 + row) * 64 + swz(row, l8 * 8),
                     &ph_s[0][wv * 512]);
        #pragma unroll
        for (int q = 0; q < 4; ++q) {
            int chunk = wv * 4 + q, c = chunk * 8 + lsub;
            async_copy16(gPT + (size_t)(b * 256 + c) * 1024 + swz(c, l8 * 8),
                         &gs[0][chunk * 512]);
        }
    }
    asm volatile("s_waitcnt vmcnt(5)" ::: "memory");   // theta landed (chunk0 may fly)
    __builtin_amdgcn_sched_barrier(0);
    __builtin_amdgcn_s_barrier();
    __builtin_amdgcn_sched_barrier(0);

    short8 thf[4][2];
    #pragma unroll
    for (int mi = 0; mi < 4; ++mi)
        #pragma unroll
        for (int ks = 0; ks < 2; ++ks)
            thf[mi][ks] = *(const short8*)&th_es[(jh * 64 + mi * 16 + r16) * 64
                                                 + swz(r16, ks * 32 + q8 * 8)];
    asm volatile("s_waitcnt lgkmcnt(0)" ::: "memory"); // my theta reads retired
    __builtin_amdgcn_sched_barrier(0);

    floatx4 acc[4][4] = {};

    for (int t = 0; t < 16; ++t) {
        const int buf = t & 1, nbuf = buf ^ 1;
        // issue next chunk's staging into nbuf (PV of t-1 finished with it,
        // end-of-iter barrier below ordered that)
        if (t < 15) {
            const int i0n = (t + 1) * 64;
            int row = wv * 8 + lsub;
            async_copy16(phiP + (size_t)(b * 1024 + i0n + row) * 64 + swz(row, l8 * 8),
                         &ph_s[nbuf][wv * 512]);
            #pragma unroll
            for (int q = 0; q < 4; ++q) {
                int chunk = wv * 4 + q, c = chunk * 8 + lsub;
                async_copy16(gPT + (size_t)(b * 256 + c) * 1024 + i0n + swz(c, l8 * 8),
                             &gs[nbuf][chunk * 512]);
            }
            asm volatile("s_waitcnt vmcnt(5)" ::: "memory");   // chunk t landed
        } else {
            asm volatile("s_waitcnt vmcnt(0)" ::: "memory");   // last chunk landed
        }
        __builtin_amdgcn_sched_barrier(0);
        __builtin_amdgcn_s_barrier();   // all waves: chunk t staged; thf reads done (t=0)
        __builtin_amdgcn_sched_barrier(0);

        // QK^T: s tile [128 j][64 i]; wave (jh, it) computes j jh*64.. x i it*16..
        floatx4 sacc[4] = {};
        #pragma unroll
        for (int ks = 0; ks < 2; ++ks) {
            short8 pf = *(const short8*)&ph_s[buf][(it * 16 + r16) * 64
                                                   + swz(r16, ks * 32 + q8 * 8)];
            #pragma unroll
            for (int mi = 0; mi < 4; ++mi)
                sacc[mi] = __builtin_amdgcn_mfma_f32_16x16x32_bf16(
                    thf[mi][ks], pf, sacc[mi], 0, 0, 0);
        }
        // es[j][i] = exp(s - 20), swizzled store (conflict-free)
        #pragma unroll
        for (int mi = 0; mi < 4; ++mi)
            #pragma unroll
            for (int r = 0; r < 4; ++r) {
                int j = jh * 64 + mi * 16 + q8 * 4 + r;     // (j>>2)&3 == q8
                th_es[j * 64 + (((it ^ q8) << 4) | r16)] = f2bf(__expf(sacc[mi][r] - 20.f));
            }
        asm volatile("s_waitcnt lgkmcnt(0)" ::: "memory");  // my es writes visible
        __builtin_amdgcn_sched_barrier(0);
        __builtin_amdgcn_s_barrier();   // es ready for all waves
        __builtin_amdgcn_sched_barrier(0);

        // o += es . gs^T   (wave: j-rows jh*64.., c-cols it*64..)
        #pragma unroll
        for (int ks = 0; ks < 2; ++ks) {
            short8 ef[4], gf[4];
            #pragma unroll
            for (int mi = 0; mi < 4; ++mi)
                ef[mi] = *(const short8*)&th_es[(jh * 64 + mi * 16 + r16) * 64
                                                + swz(r16, ks * 32 + q8 * 8)];
            #pragma unroll
            for (int ni = 0; ni < 4; ++ni)
                gf[ni] = *(const short8*)&gs[buf][(it * 64 + ni * 16 + r16) * 64
                                                  + swz(r16, ks * 32 + q8 * 8)];
            #pragma unroll
            for (int mi = 0; mi < 4; ++mi)
                #pragma unroll
                for (int ni = 0; ni < 4; ++ni)
                    acc[mi][ni] = __builtin_amdgcn_mfma_f32_16x16x32_bf16(
                        ef[mi], gf[ni], acc[mi][ni], 0, 0, 0);
        }
        asm volatile("s_waitcnt lgkmcnt(0)" ::: "memory");  // my es/gs reads retired
        __builtin_amdgcn_sched_barrier(0);
        __builtin_amdgcn_s_barrier();   // es + gs[buf] reusable next iter
        __builtin_amdgcn_sched_barrier(0);
    }

    #pragma unroll
    for (int mi = 0; mi < 4; ++mi)
        #pragma unroll
        for (int ni = 0; ni < 4; ++ni)
            #pragma unroll
            for (int r = 0; r < 4; ++r) {
                int j = j0 + jh * 64 + mi * 16 + q8 * 4 + r;
                int c = it * 64 + ni * 16 + r16;
                o_[((size_t)b * 4096 + j) * 256 + c] = f2bf(acc[mi][ni][r]);
            }
}

// ---------------------------------------------------------------------------
// prep: weight transpose+cast [384][512] (theta|phi|g), o3wT [512][256],
// fused bias [384], zero lbuf.
// ---------------------------------------------------------------------------
__global__ __launch_bounds__(256) void prep_w_kernel(
    const float* __restrict__ theta_w, const float* __restrict__ phi_w,
    const float* __restrict__ g_w, const float* __restrict__ o3_w,
    const float* __restrict__ theta_b, const float* __restrict__ phi_b,
    const float* __restrict__ g_b,
    unsigned short* __restrict__ tpgwT, unsigned short* __restrict__ o3wT,
    float* __restrict__ biasTPG, float* __restrict__ lbuf)
{
    int t = blockIdx.x * 256 + threadIdx.x;
    if (t < 196608) {                      // tpgwT [384][512]
        int n = t >> 9, k = t & 511;
        float v = (n < 64) ? theta_w[k * 64 + n]
                : (n < 128) ? phi_w[k * 64 + (n - 64)]
                : g_w[k * 256 + (n - 128)];
        tpgwT[t] = f2bf(v);
    } else if (t < 327680) {               // o3wT [512][256]
        int e = t - 196608; int n = e >> 8, k = e & 255;
        o3wT[e] = f2bf(o3_w[k * 512 + n]);
    } else if (t < 328064) {               // biasTPG [384]
        int j = t - 327680;
        biasTPG[j] = (j < 64) ? theta_b[j] : (j < 128) ? phi_b[j - 64] : g_b[j - 128];
    } else if (t < 336256) {
        lbuf[t - 328064] = 0.f;
    }
}

// phi maxpool: tpgF cols [64,128) -> phiP [8][1024][64] bf16
__global__ __launch_bounds__(256) void maxpool_phi_kernel(
    const unsigned short* __restrict__ tpgF, unsigned short* __restrict__ phiP)
{
    int t = blockIdx.x * 256 + threadIdx.x;   // 524288
    int f = t & 63, i = (t >> 6) & 1023, b = t >> 16;
    int ph = i >> 5, pw = i & 31;
    size_t base = ((size_t)(b * 64 + 2 * ph) * 64 + 2 * pw) * 384 + 64 + f;
    float v0 = bf2f(tpgF[base]),         v1 = bf2f(tpgF[base + 384]);
    float v2 = bf2f(tpgF[base + 24576]), v3 = bf2f(tpgF[base + 24576 + 384]);
    phiP[t] = f2bf(fmaxf(fmaxf(v0, v1), fmaxf(v2, v3)));
}

// g maxpool + transpose + 1/l scale: tpgF cols [128,384) -> gPT [8][256][1024]
__global__ __launch_bounds__(256) void maxpoolT_g_kernel(
    const unsigned short* __restrict__ tpgF, const float* __restrict__ lbuf,
    unsigned short* __restrict__ gPT)
{
    __shared__ unsigned short tile[16][256];
    __shared__ float rls[16];
    int b = blockIdx.y, i0 = blockIdx.x * 16, c = threadIdx.x;
    if (c < 16) rls[c] = 1.0f / lbuf[b * 1024 + i0 + c];
    __syncthreads();
    #pragma unroll
    for (int il = 0; il < 16; ++il) {
        int i = i0 + il, ph = i >> 5, pw = i & 31;
        size_t base = ((size_t)(b * 64 + 2 * ph) * 64 + 2 * pw) * 384 + 128 + c;
        float v0 = bf2f(tpgF[base]),         v1 = bf2f(tpgF[base + 384]);
        float v2 = bf2f(tpgF[base + 24576]), v3 = bf2f(tpgF[base + 24576 + 384]);
        tile[il][c] = f2bf(fmaxf(fmaxf(v0, v1), fmaxf(v2, v3)) * rls[il]);
    }
    __syncthreads();
    unsigned short* dst = gPT + ((size_t)(b * 256 + c) * 1024 + i0);
    short8 v0, v1;
    #pragma unroll
    for (int il = 0; il < 8; ++il) { v0[il] = (short)tile[il][c]; v1[il] = (short)tile[il + 8][c]; }
    *(short8*)dst = v0;
    *(short8*)(dst + 8) = v1;
}

// ---------------------------------------------------------------------------
extern "C" void kernel_launch(void* const* d_in, const int* in_sizes, int n_in,
                              void* d_out, int out_size, void* d_ws, size_t ws_size,
                              hipStream_t stream)
{
    const float* x       = (const float*)d_in[0];
    const float* theta_w = (const float*)d_in[1];
    const float* theta_b = (const float*)d_in[2];
    const float* phi_w   = (const float*)d_in[3];
    const float* phi_b   = (const float*)d_in[4];
    const float* g_w     = (const float*)d_in[5];
    const float* g_b     = (const float*)d_in[6];
    const float* o3_w    = (const float*)d_in[7];
    const float* o3_b    = (const float*)d_in[8];
    const float* gamma   = (const float*)d_in[9];

    char* ws = (char*)d_ws;
    unsigned short* tpgwT  = (unsigned short*)(ws);             // 384x512 bf16
    unsigned short* o3wT   = (unsigned short*)(ws + 393216);    // 512x256
    float* biasTPG         = (float*)(ws + 655360);             // 384
    float* lbuf            = (float*)(ws + 656896);             // 8192
    unsigned short* tpgF   = (unsigned short*)(ws + (1u << 20));            // 24 MiB
    unsigned short* phiP   = (unsigned short*)(ws + (1u << 20) + 25165824); // 1 MiB
    unsigned short* gPT    = (unsigned short*)(ws + (1u << 20) + 26214400); // 4 MiB
    unsigned short* o_     = (unsigned short*)(ws + (1u << 20) + 30408704); // 16 MiB

    // 1. weight prep + lbuf zero
    prep_w_kernel<<<1314, 256, 0, stream>>>(theta_w, phi_w, g_w, o3_w,
                                            theta_b, phi_b, g_b,
                                            tpgwT, o3wT, biasTPG, lbuf);
    // 2. fused projections: tpgF = x . tpgwT^T + bias  [32768][384]
    mfma_gemm<true, 1><<<dim3(3, 256), 256, 0, stream>>>(
        x, tpgwT, tpgF, biasTPG, nullptr, nullptr, 512, 512, 384, 512);
    // 3. phi pool
    maxpool_phi_kernel<<<2048, 256, 0, stream>>>(tpgF, phiP);
    // 4. phase 1: l[b][i] = sum_j exp(theta[j].phi[i] - 20)
    phase1_l_kernel<<<dim3(4, 16, 8), 256, 0, stream>>>(tpgF, phiP, lbuf);
    // 5. g pool + transpose + 1/l scale
    maxpoolT_g_kernel<<<dim3(64, 8), 256, 0, stream>>>(tpgF, lbuf, gPT);
    // 6. phase 2: fused e-recompute + o = e . g'   [8][4096][256]
    attn_fused_kernel<<<dim3(32, 8), 512, 0, stream>>>(tpgF, phiP, gPT, o_);
    // 7. out = gamma*(o . o3wT^T + o3_b) + x   [32768][512] fp32
    mfma_gemm<false, 2><<<dim3(4, 256), 256, 0, stream>>>(
        o_, o3wT, d_out, o3_b, gamma, x, 256, 256, 512, 256);
}

// Round 3
// 226.236 us; speedup vs baseline: 1.0430x; 1.0303x over previous
//
#include <hip/hip_runtime.h>
#include <cstdint>

typedef short short8 __attribute__((ext_vector_type(8)));
typedef float floatx4 __attribute__((ext_vector_type(4)));

__device__ __forceinline__ unsigned short f2bf(float f) {
    unsigned int u = __builtin_bit_cast(unsigned int, f);
    u += 0x7FFFu + ((u >> 16) & 1u);
    return (unsigned short)(u >> 16);
}
__device__ __forceinline__ float bf2f(unsigned short h) {
    unsigned int u = ((unsigned int)h) << 16;
    return __builtin_bit_cast(float, u);
}

__device__ __forceinline__ void async_copy16(const void* g, void* lds) {
    __builtin_amdgcn_global_load_lds(
        (const __attribute__((address_space(1))) void*)g,
        (__attribute__((address_space(3))) void*)lds, 16, 0, 0);
}

// XOR swizzle (16-short granularity): slot koff = koff ^ (((row>>2)&3)<<4)
__device__ __forceinline__ int swz(int row, int koff) {
    return koff ^ (((row >> 2) & 3) << 4);
}

// ---------------------------------------------------------------------------
// N-fused pipelined GEMM. Each block: 128 rows x full N. C[m,n]=sum_k A[m,k]B[n,k]
// Grid = M/128 = 256 blocks (1/CU) -> every A row fetched exactly once.
// Double-buffered LDS, counted vmcnt (T3/T4), 2 raw barriers/iter; loads for
// iter t+1 are issued at top of iter t and waited at top of t+1 (full-iter
// in-flight window: 8 waves x NPI x 1KiB = 80/40 KiB per CU).
// AFP32: A fp32 -> regs -> cvt -> ds_write (T14 split). EPI: 1 = bf16 +bias;
// 2 = fp32 gamma*(v+bias)+resid.
// ---------------------------------------------------------------------------
template<bool AFP32, int EPI, int BN, int BK, int NT>
__global__ __launch_bounds__(512, 2) void gemm_nf(
    const void* __restrict__ Avoid, const unsigned short* __restrict__ B,
    void* __restrict__ Cout, const float* __restrict__ bias,
    const float* __restrict__ gammap, const float* __restrict__ resid,
    int lda, int ldb, int ldc)
{
    constexpr int NI = BN / 64;              // n-frags per wave (wave n-width BN/4)
    constexpr int KS = BK / 32;              // 32-k MFMA steps per iter
    constexpr int SLOTM = BK / 16 - 1;       // swizzle slot mask for BK-short rows
    constexpr int NB = BN * BK / 4096;       // B dma instrs / wave / iter
    constexpr int NPI = NB + (AFP32 ? BK / 16 : BK / 32);  // issues / wave / iter

    __shared__ unsigned short As[2][128 * BK];
    __shared__ unsigned short Bs[2][BN * BK];

    const int tid = threadIdx.x;
    const int wv = tid >> 6, ln = tid & 63;
    const int r16 = ln & 15, q8 = ln >> 4;
    const int wr = wv >> 2, wc = wv & 3;     // 2(m) x 4(n) wave grid
    const int m0 = blockIdx.x * 128;

    const float* Af = (const float*)Avoid;
    const unsigned short* Ag = (const unsigned short*)Avoid;

    auto swzT = [](int row, int koff) { return koff ^ (((row >> 2) & SLOTM) << 4); };

    float4 areg[AFP32 ? BK / 16 : 1];

    auto stageB = [&](int t, int sb) {
        const int k0 = t * BK;
        #pragma unroll
        for (int q = 0; q < NB; ++q) {
            int c = wv * NB + q;
            if (BK == 64) {                  // 8 rows of 64 shorts per chunk
                int row = c * 8 + (ln >> 3), l8 = ln & 7;
                async_copy16(B + (size_t)row * ldb + k0 + swzT(row, l8 * 8),
                             &Bs[sb][c * 512]);
            } else {                         // BK==32: 16 rows of 32 shorts
                int row = c * 16 + (ln >> 2), sl = ln & 3;
                async_copy16(B + (size_t)row * ldb + k0 + swzT(row, sl * 8),
                             &Bs[sb][c * 512]);
            }
        }
    };
    auto stageA_dma = [&](int t, int sb) {   // !AFP32 (BK==32): 1 instr/lane
        const int k0 = t * BK;
        int row = wv * 16 + (ln >> 2), sl = ln & 3;
        async_copy16(Ag + (size_t)(m0 + row) * lda + k0 + swzT(row, sl * 8),
                     &As[sb][wv * 512]);
    };
    auto loadA_reg = [&](int t) {            // AFP32: 4 float4/lane
        const int k0 = t * BK;
        #pragma unroll
        for (int p = 0; p < BK / 16; ++p) {
            int idx = p * 512 + tid;
            int row = idx >> 4, c4 = idx & 15;
            areg[p] = *(const float4*)(Af + (size_t)(m0 + row) * lda + k0 + c4 * 4);
        }
    };
    auto writeA = [&](int sb) {
        #pragma unroll
        for (int p = 0; p < BK / 16; ++p) {
            int idx = p * 512 + tid;
            int row = idx >> 4, c4 = idx & 15;
            ushort4 h;
            h.x = f2bf(areg[p].x); h.y = f2bf(areg[p].y);
            h.z = f2bf(areg[p].z); h.w = f2bf(areg[p].w);
            *(ushort4*)&As[sb][row * BK + swzT(row, c4 * 4)] = h;
        }
    };

    // ---- prologue: stage chunk 0 ----
    if (AFP32) loadA_reg(0); else stageA_dma(0, 0);
    stageB(0, 0);
    if (AFP32) {
        asm volatile("s_waitcnt vmcnt(%0)" :: "i"(NB) : "memory");  // A(0) regs in
        __builtin_amdgcn_sched_barrier(0);
        writeA(0);
        asm volatile("s_waitcnt lgkmcnt(0)" ::: "memory");
        __builtin_amdgcn_sched_barrier(0);
    }

    floatx4 acc[4][NI] = {};

    for (int t = 0; t < NT; ++t) {
        const int buf = t & 1, nbuf = buf ^ 1;
        // issue chunk t+1 (lands during this iter's compute)
        if (t < NT - 1) {
            if (AFP32) loadA_reg(t + 1); else stageA_dma(t + 1, nbuf);
            stageB(t + 1, nbuf);
            asm volatile("s_waitcnt vmcnt(%0)" :: "i"(NPI) : "memory"); // chunk t landed
        } else {
            asm volatile("s_waitcnt vmcnt(0)" ::: "memory");
        }
        __builtin_amdgcn_sched_barrier(0);
        __builtin_amdgcn_s_barrier();        // chunk t visible to all waves
        __builtin_amdgcn_sched_barrier(0);

        #pragma unroll
        for (int ks = 0; ks < KS; ++ks) {
            short8 af[4], bf[NI];
            #pragma unroll
            for (int mi = 0; mi < 4; ++mi) {
                int row = wr * 64 + mi * 16 + r16;
                af[mi] = *(const short8*)&As[buf][row * BK + swzT(row, ks * 32 + q8 * 8)];
            }
            #pragma unroll
            for (int ni = 0; ni < NI; ++ni) {
                int n = wc * (BN / 4) + ni * 16 + r16;
                bf[ni] = *(const short8*)&Bs[buf][n * BK + swzT(n, ks * 32 + q8 * 8)];
            }
            __builtin_amdgcn_s_setprio(1);
            #pragma unroll
            for (int mi = 0; mi < 4; ++mi)
                #pragma unroll
                for (int ni = 0; ni < NI; ++ni)
                    acc[mi][ni] = __builtin_amdgcn_mfma_f32_16x16x32_bf16(
                        af[mi], bf[ni], acc[mi][ni], 0, 0, 0);
            __builtin_amdgcn_s_setprio(0);
        }

        if (AFP32 && t < NT - 1) {
            asm volatile("s_waitcnt vmcnt(%0)" :: "i"(NB) : "memory"); // A(t+1) regs in
            __builtin_amdgcn_sched_barrier(0);
            writeA(nbuf);
        }
        asm volatile("s_waitcnt lgkmcnt(0)" ::: "memory");  // ds_writes + reads retired
        __builtin_amdgcn_sched_barrier(0);
        __builtin_amdgcn_s_barrier();        // buf reusable / nbuf writes ordered
        __builtin_amdgcn_sched_barrier(0);
    }

    if (EPI == 2) {
        float* C = (float*)Cout;
        const float gm = gammap[0];
        #pragma unroll
        for (int ni = 0; ni < NI; ++ni) {
            const int n = wc * (BN / 4) + ni * 16 + r16;
            const float bs = bias[n];
            #pragma unroll
            for (int mi = 0; mi < 4; ++mi)
                #pragma unroll
                for (int r = 0; r < 4; ++r) {
                    int m = m0 + wr * 64 + mi * 16 + q8 * 4 + r;
                    C[(size_t)m * ldc + n] = gm * (acc[mi][ni][r] + bs) + resid[(size_t)m * ldc + n];
                }
        }
    } else {
        unsigned short* C = (unsigned short*)Cout;
        #pragma unroll
        for (int ni = 0; ni < NI; ++ni) {
            const int n = wc * (BN / 4) + ni * 16 + r16;
            const float bs = bias[n];
            #pragma unroll
            for (int mi = 0; mi < 4; ++mi)
                #pragma unroll
                for (int r = 0; r < 4; ++r) {
                    int m = m0 + wr * 64 + mi * 16 + q8 * 4 + r;
                    C[(size_t)m * ldc + n] = f2bf(acc[mi][ni][r] + bs);
                }
        }
    }
}

// ---------------------------------------------------------------------------
// Phase 1: l[b][i] = sum_j exp(theta[b,j].phi[b,i] - 20)
// Grid (4 j-splits, 16 i-tiles of 64, 8 b) = 512 blocks.
// ---------------------------------------------------------------------------
__global__ __launch_bounds__(256) void phase1_l_kernel(
    const unsigned short* __restrict__ tpgF,   // [32768][384], theta cols 0..63
    const unsigned short* __restrict__ phiP,   // [8][1024][64]
    float* __restrict__ lbuf)                  // [8][1024] (pre-zeroed)
{
    __shared__ unsigned short th_s[8192];   // [128][64]
    __shared__ unsigned short ph_s[4096];   // [64][64]
    const int tid = threadIdx.x, wv = tid >> 6, ln = tid & 63;
    const int r16 = ln & 15, q8 = ln >> 4, lsub = ln >> 3, l8 = ln & 7;
    const int jsp = blockIdx.x, i0 = blockIdx.y * 64, b = blockIdx.z;

    #pragma unroll
    for (int q = 0; q < 2; ++q) {
        int chunk = wv * 2 + q, row = chunk * 8 + lsub;
        int so = swz(row, l8 * 8);
        async_copy16(phiP + (size_t)(b * 1024 + i0 + row) * 64 + so, &ph_s[chunk * 512]);
    }

    float colsum[4] = {0.f, 0.f, 0.f, 0.f};
    for (int jc = 0; jc < 8; ++jc) {
        const int j0 = jsp * 1024 + jc * 128;
        __syncthreads();
        #pragma unroll
        for (int q = 0; q < 4; ++q) {
            int chunk = wv * 4 + q, row = chunk * 8 + lsub;
            int so = swz(row, l8 * 8);
            async_copy16(tpgF + (size_t)(b * 4096 + j0 + row) * 384 + so, &th_s[chunk * 512]);
        }
        __syncthreads();

        floatx4 sacc[2][4] = {};
        #pragma unroll
        for (int ks = 0; ks < 2; ++ks) {
            short8 af[2], bf[4];
            #pragma unroll
            for (int mi = 0; mi < 2; ++mi)
                af[mi] = *(const short8*)&th_s[(wv * 32 + mi * 16 + r16) * 64 + swz(r16, ks * 32 + q8 * 8)];
            #pragma unroll
            for (int ni = 0; ni < 4; ++ni)
                bf[ni] = *(const short8*)&ph_s[(ni * 16 + r16) * 64 + swz(r16, ks * 32 + q8 * 8)];
            #pragma unroll
            for (int mi = 0; mi < 2; ++mi)
                #pragma unroll
                for (int ni = 0; ni < 4; ++ni)
                    sacc[mi][ni] = __builtin_amdgcn_mfma_f32_16x16x32_bf16(
                        af[mi], bf[ni], sacc[mi][ni], 0, 0, 0);
        }
        #pragma unroll
        for (int mi = 0; mi < 2; ++mi)
            #pragma unroll
            for (int ni = 0; ni < 4; ++ni)
                #pragma unroll
                for (int r = 0; r < 4; ++r)
                    colsum[ni] += __expf(sacc[mi][ni][r] - 20.f);
    }
    #pragma unroll
    for (int ni = 0; ni < 4; ++ni) {
        float s = colsum[ni];
        s += __shfl_xor(s, 16);
        s += __shfl_xor(s, 32);
        if (q8 == 0) atomicAdd(&lbuf[b * 1024 + i0 + ni * 16 + r16], s);
    }
}

// ---------------------------------------------------------------------------
// Fused attention phase 2: o[b,j,c] = sum_i exp(theta[j].phi[i]-20) * g'[c,i]
// (g' pre-scaled by 1/l). j-tile 128, 8 waves (512 thr), i chunks of 64,
// double-buffered ph/gs staging with counted vmcnt (T3/T4 2-phase pipeline).
// Grid (32, 8) = 256 blocks, 96 KiB LDS, 1 block/CU.
// ---------------------------------------------------------------------------
__global__ __launch_bounds__(512) void attn_fused_kernel(
    const unsigned short* __restrict__ tpgF,  // [32768][384], theta cols 0..63
    const unsigned short* __restrict__ phiP,  // [8][1024][64]
    const unsigned short* __restrict__ gPT,   // [8][256][1024], pre-scaled 1/l
    unsigned short* __restrict__ o_)          // [8][4096][256]
{
    __shared__ unsigned short th_es[8192];     // theta [128][64], then es (aliased)
    __shared__ unsigned short ph_s[2][4096];   // phi chunk [64][64] x2
    __shared__ unsigned short gs[2][16384];    // g chunk [256][64] x2

    const int tid = threadIdx.x, wv = tid >> 6, ln = tid & 63;
    const int r16 = ln & 15, q8 = ln >> 4, lsub = ln >> 3, l8 = ln & 7;
    const int j0 = blockIdx.x * 128, b = blockIdx.y;
    const int jh = wv >> 2, it = wv & 3;  // j-half (QK/PV rows), i-tile / c-quarter

    // prologue: stage theta [128][64] (2/wave) + chunk0 ph+gs (5/wave)
    #pragma unroll
    for (int q = 0; q < 2; ++q) {
        int chunk = wv * 2 + q, row = chunk * 8 + lsub;
        async_copy16(tpgF + (size_t)(b * 4096 + j0 + row) * 384 + swz(row, l8 * 8),
                     &th_es[chunk * 512]);
    }
    {
        int row = wv * 8 + lsub;
        async_copy16(phiP + (size_t)(b * 1024 + row) * 64 + swz(row, l8 * 8),
                     &ph_s[0][wv * 512]);
        #pragma unroll
        for (int q = 0; q < 4; ++q) {
            int chunk = wv * 4 + q, c = chunk * 8 + lsub;
            async_copy16(gPT + (size_t)(b * 256 + c) * 1024 + swz(c, l8 * 8),
                         &gs[0][chunk * 512]);
        }
    }
    asm volatile("s_waitcnt vmcnt(5)" ::: "memory");   // theta landed (chunk0 may fly)
    __builtin_amdgcn_sched_barrier(0);
    __builtin_amdgcn_s_barrier();
    __builtin_amdgcn_sched_barrier(0);

    short8 thf[4][2];
    #pragma unroll
    for (int mi = 0; mi < 4; ++mi)
        #pragma unroll
        for (int ks = 0; ks < 2; ++ks)
            thf[mi][ks] = *(const short8*)&th_es[(jh * 64 + mi * 16 + r16) * 64
                                                 + swz(r16, ks * 32 + q8 * 8)];
    asm volatile("s_waitcnt lgkmcnt(0)" ::: "memory"); // my theta reads retired
    __builtin_amdgcn_sched_barrier(0);

    floatx4 acc[4][4] = {};

    for (int t = 0; t < 16; ++t) {
        const int buf = t & 1, nbuf = buf ^ 1;
        // issue next chunk's staging into nbuf (PV of t-1 finished with it,
        // end-of-iter barrier below ordered that)
        if (t < 15) {
            const int i0n = (t + 1) * 64;
            int row = wv * 8 + lsub;
            async_copy16(phiP + (size_t)(b * 1024 + i0n + row) * 64 + swz(row, l8 * 8),
                         &ph_s[nbuf][wv * 512]);
            #pragma unroll
            for (int q = 0; q < 4; ++q) {
                int chunk = wv * 4 + q, c = chunk * 8 + lsub;
                async_copy16(gPT + (size_t)(b * 256 + c) * 1024 + i0n + swz(c, l8 * 8),
                             &gs[nbuf][chunk * 512]);
            }
            asm volatile("s_waitcnt vmcnt(5)" ::: "memory");   // chunk t landed
        } else {
            asm volatile("s_waitcnt vmcnt(0)" ::: "memory");   // last chunk landed
        }
        __builtin_amdgcn_sched_barrier(0);
        __builtin_amdgcn_s_barrier();   // all waves: chunk t staged; thf reads done (t=0)
        __builtin_amdgcn_sched_barrier(0);

        // QK^T: s tile [128 j][64 i]; wave (jh, it) computes j jh*64.. x i it*16..
        floatx4 sacc[4] = {};
        #pragma unroll
        for (int ks = 0; ks < 2; ++ks) {
            short8 pf = *(const short8*)&ph_s[buf][(it * 16 + r16) * 64
                                                   + swz(r16, ks * 32 + q8 * 8)];
            #pragma unroll
            for (int mi = 0; mi < 4; ++mi)
                sacc[mi] = __builtin_amdgcn_mfma_f32_16x16x32_bf16(
                    thf[mi][ks], pf, sacc[mi], 0, 0, 0);
        }
        // es[j][i] = exp(s - 20), swizzled store (conflict-free)
        #pragma unroll
        for (int mi = 0; mi < 4; ++mi)
            #pragma unroll
            for (int r = 0; r < 4; ++r) {
                int j = jh * 64 + mi * 16 + q8 * 4 + r;     // (j>>2)&3 == q8
                th_es[j * 64 + (((it ^ q8) << 4) | r16)] = f2bf(__expf(sacc[mi][r] - 20.f));
            }
        asm volatile("s_waitcnt lgkmcnt(0)" ::: "memory");  // my es writes visible
        __builtin_amdgcn_sched_barrier(0);
        __builtin_amdgcn_s_barrier();   // es ready for all waves
        __builtin_amdgcn_sched_barrier(0);

        // o += es . gs^T   (wave: j-rows jh*64.., c-cols it*64..)
        #pragma unroll
        for (int ks = 0; ks < 2; ++ks) {
            short8 ef[4], gf[4];
            #pragma unroll
            for (int mi = 0; mi < 4; ++mi)
                ef[mi] = *(const short8*)&th_es[(jh * 64 + mi * 16 + r16) * 64
                                                + swz(r16, ks * 32 + q8 * 8)];
            #pragma unroll
            for (int ni = 0; ni < 4; ++ni)
                gf[ni] = *(const short8*)&gs[buf][(it * 64 + ni * 16 + r16) * 64
                                                  + swz(r16, ks * 32 + q8 * 8)];
            #pragma unroll
            for (int mi = 0; mi < 4; ++mi)
                #pragma unroll
                for (int ni = 0; ni < 4; ++ni)
                    acc[mi][ni] = __builtin_amdgcn_mfma_f32_16x16x32_bf16(
                        ef[mi], gf[ni], acc[mi][ni], 0, 0, 0);
        }
        asm volatile("s_waitcnt lgkmcnt(0)" ::: "memory");  // my es/gs reads retired
        __builtin_amdgcn_sched_barrier(0);
        __builtin_amdgcn_s_barrier();   // es + gs[buf] reusable next iter
        __builtin_amdgcn_sched_barrier(0);
    }

    #pragma unroll
    for (int mi = 0; mi < 4; ++mi)
        #pragma unroll
        for (int ni = 0; ni < 4; ++ni)
            #pragma unroll
            for (int r = 0; r < 4; ++r) {
                int j = j0 + jh * 64 + mi * 16 + q8 * 4 + r;
                int c = it * 64 + ni * 16 + r16;
                o_[((size_t)b * 4096 + j) * 256 + c] = f2bf(acc[mi][ni][r]);
            }
}

// ---------------------------------------------------------------------------
// prep: weight transpose+cast [384][512] (theta|phi|g), o3wT [512][256],
// fused bias [384], zero lbuf.
// ---------------------------------------------------------------------------
__global__ __launch_bounds__(256) void prep_w_kernel(
    const float* __restrict__ theta_w, const float* __restrict__ phi_w,
    const float* __restrict__ g_w, const float* __restrict__ o3_w,
    const float* __restrict__ theta_b, const float* __restrict__ phi_b,
    const float* __restrict__ g_b,
    unsigned short* __restrict__ tpgwT, unsigned short* __restrict__ o3wT,
    float* __restrict__ biasTPG, float* __restrict__ lbuf)
{
    int t = blockIdx.x * 256 + threadIdx.x;
    if (t < 196608) {                      // tpgwT [384][512]
        int n = t >> 9, k = t & 511;
        float v = (n < 64) ? theta_w[k * 64 + n]
                : (n < 128) ? phi_w[k * 64 + (n - 64)]
                : g_w[k * 256 + (n - 128)];
        tpgwT[t] = f2bf(v);
    } else if (t < 327680) {               // o3wT [512][256]
        int e = t - 196608; int n = e >> 8, k = e & 255;
        o3wT[e] = f2bf(o3_w[k * 512 + n]);
    } else if (t < 328064) {               // biasTPG [384]
        int j = t - 327680;
        biasTPG[j] = (j < 64) ? theta_b[j] : (j < 128) ? phi_b[j - 64] : g_b[j - 128];
    } else if (t < 336256) {
        lbuf[t - 328064] = 0.f;
    }
}

// phi maxpool: tpgF cols [64,128) -> phiP [8][1024][64] bf16
__global__ __launch_bounds__(256) void maxpool_phi_kernel(
    const unsigned short* __restrict__ tpgF, unsigned short* __restrict__ phiP)
{
    int t = blockIdx.x * 256 + threadIdx.x;   // 524288
    int f = t & 63, i = (t >> 6) & 1023, b = t >> 16;
    int ph = i >> 5, pw = i & 31;
    size_t base = ((size_t)(b * 64 + 2 * ph) * 64 + 2 * pw) * 384 + 64 + f;
    float v0 = bf2f(tpgF[base]),         v1 = bf2f(tpgF[base + 384]);
    float v2 = bf2f(tpgF[base + 24576]), v3 = bf2f(tpgF[base + 24576 + 384]);
    phiP[t] = f2bf(fmaxf(fmaxf(v0, v1), fmaxf(v2, v3)));
}

// g maxpool + transpose + 1/l scale: tpgF cols [128,384) -> gPT [8][256][1024]
__global__ __launch_bounds__(256) void maxpoolT_g_kernel(
    const unsigned short* __restrict__ tpgF, const float* __restrict__ lbuf,
    unsigned short* __restrict__ gPT)
{
    __shared__ unsigned short tile[16][256];
    __shared__ float rls[16];
    int b = blockIdx.y, i0 = blockIdx.x * 16, c = threadIdx.x;
    if (c < 16) rls[c] = 1.0f / lbuf[b * 1024 + i0 + c];
    __syncthreads();
    #pragma unroll
    for (int il = 0; il < 16; ++il) {
        int i = i0 + il, ph = i >> 5, pw = i & 31;
        size_t base = ((size_t)(b * 64 + 2 * ph) * 64 + 2 * pw) * 384 + 128 + c;
        float v0 = bf2f(tpgF[base]),         v1 = bf2f(tpgF[base + 384]);
        float v2 = bf2f(tpgF[base + 24576]), v3 = bf2f(tpgF[base + 24576 + 384]);
        tile[il][c] = f2bf(fmaxf(fmaxf(v0, v1), fmaxf(v2, v3)) * rls[il]);
    }
    __syncthreads();
    unsigned short* dst = gPT + ((size_t)(b * 256 + c) * 1024 + i0);
    short8 v0, v1;
    #pragma unroll
    for (int il = 0; il < 8; ++il) { v0[il] = (short)tile[il][c]; v1[il] = (short)tile[il + 8][c]; }
    *(short8*)dst = v0;
    *(short8*)(dst + 8) = v1;
}

// ---------------------------------------------------------------------------
extern "C" void kernel_launch(void* const* d_in, const int* in_sizes, int n_in,
                              void* d_out, int out_size, void* d_ws, size_t ws_size,
                              hipStream_t stream)
{
    const float* x       = (const float*)d_in[0];
    const float* theta_w = (const float*)d_in[1];
    const float* theta_b = (const float*)d_in[2];
    const float* phi_w   = (const float*)d_in[3];
    const float* phi_b   = (const float*)d_in[4];
    const float* g_w     = (const float*)d_in[5];
    const float* g_b     = (const float*)d_in[6];
    const float* o3_w    = (const float*)d_in[7];
    const float* o3_b    = (const float*)d_in[8];
    const float* gamma   = (const float*)d_in[9];

    char* ws = (char*)d_ws;
    unsigned short* tpgwT  = (unsigned short*)(ws);             // 384x512 bf16
    unsigned short* o3wT   = (unsigned short*)(ws + 393216);    // 512x256
    float* biasTPG         = (float*)(ws + 655360);             // 384
    float* lbuf            = (float*)(ws + 656896);             // 8192
    unsigned short* tpgF   = (unsigned short*)(ws + (1u << 20));            // 24 MiB
    unsigned short* phiP   = (unsigned short*)(ws + (1u << 20) + 25165824); // 1 MiB
    unsigned short* gPT    = (unsigned short*)(ws + (1u << 20) + 26214400); // 4 MiB
    unsigned short* o_     = (unsigned short*)(ws + (1u << 20) + 30408704); // 16 MiB

    // 1. weight prep + lbuf zero
    prep_w_kernel<<<1314, 256, 0, stream>>>(theta_w, phi_w, g_w, o3_w,
                                            theta_b, phi_b, g_b,
                                            tpgwT, o3wT, biasTPG, lbuf);
    // 2. fused projections: tpgF = x . tpgwT^T + bias  [32768][384]
    gemm_nf<true, 1, 384, 64, 8><<<256, 512, 0, stream>>>(
        x, tpgwT, tpgF, biasTPG, nullptr, nullptr, 512, 512, 384);
    // 3. phi pool
    maxpool_phi_kernel<<<2048, 256, 0, stream>>>(tpgF, phiP);
    // 4. phase 1: l[b][i] = sum_j exp(theta[j].phi[i] - 20)
    phase1_l_kernel<<<dim3(4, 16, 8), 256, 0, stream>>>(tpgF, phiP, lbuf);
    // 5. g pool + transpose + 1/l scale
    maxpoolT_g_kernel<<<dim3(64, 8), 256, 0, stream>>>(tpgF, lbuf, gPT);
    // 6. phase 2: fused e-recompute + o = e . g'   [8][4096][256]
    attn_fused_kernel<<<dim3(32, 8), 512, 0, stream>>>(tpgF, phiP, gPT, o_);
    // 7. out = gamma*(o . o3wT^T + o3_b) + x   [32768][512] fp32
    gemm_nf<false, 2, 512, 32, 8><<<256, 512, 0, stream>>>(
        o_, o3wT, d_out, o3_b, gamma, x, 256, 256, 512);
}